// Round 1
// baseline (1433.198 us; speedup 1.0000x reference)
//
#include <hip/hip_runtime.h>
#include <math.h>

static constexpr int IN_DIM  = 128;
static constexpr int HID     = 64;
static constexpr int OUT_F   = 32;
static constexpr int NUM_LBL = 10;

// ---------------- graph setup kernels ----------------

__global__ void count_deg_k(const int* __restrict__ dst, int* __restrict__ deg, int E) {
    int e = blockIdx.x * 256 + threadIdx.x;
    if (e < E) atomicAdd(&deg[dst[e]], 1);
}

__global__ void dinv_k(const int* __restrict__ deg, float* __restrict__ dinv, int n) {
    int i = blockIdx.x * 256 + threadIdx.x;
    if (i < n) dinv[i] = rsqrtf((float)deg[i] + 1.0f);
}

__global__ void scan_partials_k(const int* __restrict__ deg, int* __restrict__ partials, int n) {
    __shared__ int s[256];
    int i = blockIdx.x * 256 + threadIdx.x;
    s[threadIdx.x] = (i < n) ? deg[i] : 0;
    __syncthreads();
    for (int st = 128; st > 0; st >>= 1) {
        if (threadIdx.x < st) s[threadIdx.x] += s[threadIdx.x + st];
        __syncthreads();
    }
    if (threadIdx.x == 0) partials[blockIdx.x] = s[0];
}

// single block, exclusive scan in place (nb <= 512)
__global__ void scan_top_k(int* __restrict__ partials, int nb) {
    __shared__ int s[512];
    int t = threadIdx.x;
    int v = (t < nb) ? partials[t] : 0;
    s[t] = v;
    __syncthreads();
    for (int off = 1; off < 512; off <<= 1) {
        int x = (t >= off) ? s[t - off] : 0;
        __syncthreads();
        s[t] += x;
        __syncthreads();
    }
    if (t < nb) partials[t] = s[t] - v;
}

__global__ void scan_final_k(const int* __restrict__ deg, const int* __restrict__ partials,
                             int* __restrict__ row_ptr, int* __restrict__ cursor, int n, int E) {
    __shared__ int s[256];
    int t = threadIdx.x;
    int i = blockIdx.x * 256 + t;
    int v = (i < n) ? deg[i] : 0;
    s[t] = v;
    __syncthreads();
    for (int off = 1; off < 256; off <<= 1) {
        int x = (t >= off) ? s[t - off] : 0;
        __syncthreads();
        s[t] += x;
        __syncthreads();
    }
    int excl = s[t] - v + partials[blockIdx.x];
    if (i < n) { row_ptr[i] = excl; cursor[i] = excl; }
    if (i == 0) row_ptr[n] = E;
}

__global__ void fill_csr_k(const int* __restrict__ src, const int* __restrict__ dst,
                           int* __restrict__ cursor, int* __restrict__ col, int E) {
    int e = blockIdx.x * 256 + threadIdx.x;
    if (e < E) {
        int pos = atomicAdd(&cursor[dst[e]], 1);
        col[pos] = src[e];
    }
}

// ---------------- compute kernels ----------------

// g[row, col] = dinv[row] * sum_k x[row,k] * W[k,col]
template<int K, int F>
__global__ void linear_scale_k(const float* __restrict__ x, const float* __restrict__ W,
                               const float* __restrict__ dinv, float* __restrict__ g, int n) {
    __shared__ float Ws[K * F];
    for (int idx = threadIdx.x; idx < K * F; idx += 256) Ws[idx] = W[idx];
    __syncthreads();
    constexpr int RPB = 256 / F;
    int col = threadIdx.x % F;
    int row = blockIdx.x * RPB + threadIdx.x / F;
    if (row >= n) return;
    const float4* x4 = (const float4*)(x + (size_t)row * K);
    float acc = 0.f;
#pragma unroll
    for (int k4 = 0; k4 < K / 4; ++k4) {
        float4 xv = x4[k4];
        acc += xv.x * Ws[(4 * k4 + 0) * F + col];
        acc += xv.y * Ws[(4 * k4 + 1) * F + col];
        acc += xv.z * Ws[(4 * k4 + 2) * F + col];
        acc += xv.w * Ws[(4 * k4 + 3) * F + col];
    }
    g[(size_t)row * F + col] = dinv[row] * acc;
}

// out[i,f] = dinv[i] * (sum_{src in nbr(i)} g[src,f] + g[i,f]) + bias[f]; optional mask overwrite with y
template<int F, bool MASK>
__global__ void gcn_gather_k(const float* __restrict__ g, const int* __restrict__ row_ptr,
                             const int* __restrict__ col, const float* __restrict__ dinv,
                             const float* __restrict__ bias, const int* __restrict__ mask,
                             const float* __restrict__ y, float* __restrict__ out, int n) {
    constexpr int NPW = 64 / F;               // nodes per wave
    int lane = threadIdx.x & 63;
    int wid  = threadIdx.x >> 6;              // wave in block (0..3)
    int f = lane % F;
    int i = (blockIdx.x * 4 + wid) * NPW + lane / F;
    if (i >= n) return;
    int beg = row_ptr[i], end = row_ptr[i + 1];
    float acc = 0.f;
    int p = beg;
    for (; p + 4 <= end; p += 4) {
        int s0 = col[p], s1 = col[p + 1], s2 = col[p + 2], s3 = col[p + 3];
        acc += g[(size_t)s0 * F + f];
        acc += g[(size_t)s1 * F + f];
        acc += g[(size_t)s2 * F + f];
        acc += g[(size_t)s3 * F + f];
    }
    for (; p < end; ++p) acc += g[(size_t)col[p] * F + f];
    float v = dinv[i] * (acc + g[(size_t)i * F + f]) + bias[f];
    if (MASK) { if (mask[i]) v = y[(size_t)i * F + f]; }
    out[(size_t)i * F + f] = v;
}

// out[i,c] = sigmoid( [h|xl|dw] @ Wf + bf )
__global__ void fuse_k(const float* __restrict__ h, const float* __restrict__ xl,
                       const float* __restrict__ dw, const float* __restrict__ Wf,
                       const float* __restrict__ bf, float* __restrict__ out, int n) {
    __shared__ float Ws[160 * 32];
    for (int idx = threadIdx.x; idx < 160 * 32; idx += 256) Ws[idx] = Wf[idx];
    __syncthreads();
    int col = threadIdx.x & 31;
    int row = blockIdx.x * 8 + (threadIdx.x >> 5);
    if (row >= n) return;
    float acc = bf[col];
    const float4* h4 = (const float4*)(h + (size_t)row * 64);
#pragma unroll
    for (int k4 = 0; k4 < 16; ++k4) {
        float4 v = h4[k4]; int kb = k4 * 4;
        acc += v.x * Ws[(kb + 0) * 32 + col];
        acc += v.y * Ws[(kb + 1) * 32 + col];
        acc += v.z * Ws[(kb + 2) * 32 + col];
        acc += v.w * Ws[(kb + 3) * 32 + col];
    }
    const float4* x4 = (const float4*)(xl + (size_t)row * 32);
#pragma unroll
    for (int k4 = 0; k4 < 8; ++k4) {
        float4 v = x4[k4]; int kb = 64 + k4 * 4;
        acc += v.x * Ws[(kb + 0) * 32 + col];
        acc += v.y * Ws[(kb + 1) * 32 + col];
        acc += v.z * Ws[(kb + 2) * 32 + col];
        acc += v.w * Ws[(kb + 3) * 32 + col];
    }
    const float4* d4 = (const float4*)(dw + (size_t)row * 64);
#pragma unroll
    for (int k4 = 0; k4 < 16; ++k4) {
        float4 v = d4[k4]; int kb = 96 + k4 * 4;
        acc += v.x * Ws[(kb + 0) * 32 + col];
        acc += v.y * Ws[(kb + 1) * 32 + col];
        acc += v.z * Ws[(kb + 2) * 32 + col];
        acc += v.w * Ws[(kb + 3) * 32 + col];
    }
    out[(size_t)row * 32 + col] = 1.0f / (1.0f + __expf(-acc));
}

// ---------------- launch ----------------

extern "C" void kernel_launch(void* const* d_in, const int* in_sizes, int n_in,
                              void* d_out, int out_size, void* d_ws, size_t ws_size,
                              hipStream_t stream) {
    const float* x    = (const float*)d_in[0];
    const float* y    = (const float*)d_in[1];
    const int*   ei   = (const int*)  d_in[2];
    const float* dw   = (const float*)d_in[3];
    const int*   mask = (const int*)  d_in[4];
    const float* Wg0  = (const float*)d_in[5];
    const float* bg0  = (const float*)d_in[6];
    const float* Wg1  = (const float*)d_in[7];
    const float* bg1  = (const float*)d_in[8];
    const float* Wl   = (const float*)d_in[9];
    const float* bl   = (const float*)d_in[10];
    const float* Wf   = (const float*)d_in[11];
    const float* bf   = (const float*)d_in[12];
    float* out = (float*)d_out;

    const int N = in_sizes[0] / IN_DIM;
    const int E = in_sizes[2] / 2;
    const int* src = ei;
    const int* dst = ei + E;

    char* w = (char*)d_ws;
    size_t off = 0;
    auto alloc = [&](size_t bytes) -> char* {
        off = (off + 255) & ~(size_t)255;
        char* p = w + off; off += bytes; return p;
    };
    float* dinv   = (float*)alloc((size_t)N * 4);
    int*   deg    = (int*)  alloc((size_t)N * 4);
    int*   rowp   = (int*)  alloc((size_t)(N + 1) * 4);
    int*   cursor = (int*)  alloc((size_t)N * 4);
    int*   parts  = (int*)  alloc(512 * 4);
    int*   colx   = (int*)  alloc((size_t)E * 4);
    float* gbuf   = (float*)alloc((size_t)N * HID * 4);
    float* hbuf   = (float*)alloc((size_t)N * HID * 4);
    float* xlA    = (float*)alloc((size_t)N * OUT_F * 4);
    float* xlB    = (float*)alloc((size_t)N * OUT_F * 4);
    (void)ws_size; (void)n_in; (void)out_size;

    const int nbN = (N + 255) / 256;   // 391
    const int nbE = (E + 255) / 256;   // 6250

    hipMemsetAsync(deg, 0, (size_t)N * 4, stream);
    count_deg_k<<<nbE, 256, 0, stream>>>(dst, deg, E);
    dinv_k<<<nbN, 256, 0, stream>>>(deg, dinv, N);
    scan_partials_k<<<nbN, 256, 0, stream>>>(deg, parts, N);
    scan_top_k<<<1, 512, 0, stream>>>(parts, nbN);
    scan_final_k<<<nbN, 256, 0, stream>>>(deg, parts, rowp, cursor, N, E);
    fill_csr_k<<<nbE, 256, 0, stream>>>(src, dst, cursor, colx, E);

    // feature path: h = conv(conv(x, W0), W1)
    linear_scale_k<IN_DIM, HID><<<(N + 3) / 4, 256, 0, stream>>>(x, Wg0, dinv, gbuf, N);
    gcn_gather_k<HID, false><<<(N + 3) / 4, 256, 0, stream>>>(gbuf, rowp, colx, dinv, bg0, nullptr, nullptr, hbuf, N);
    linear_scale_k<HID, HID><<<(N + 3) / 4, 256, 0, stream>>>(hbuf, Wg1, dinv, gbuf, N);
    gcn_gather_k<HID, false><<<(N + 3) / 4, 256, 0, stream>>>(gbuf, rowp, colx, dinv, bg1, nullptr, nullptr, hbuf, N);

    // label path: 10 masked convs, ping-pong xlA/xlB, g reuses gbuf
    const float* xl_cur = y;
    for (int j = 0; j < NUM_LBL; ++j) {
        float* xl_out = (j & 1) ? xlB : xlA;
        linear_scale_k<OUT_F, OUT_F><<<(N + 7) / 8, 256, 0, stream>>>(xl_cur, Wl + (size_t)j * OUT_F * OUT_F, dinv, gbuf, N);
        gcn_gather_k<OUT_F, true><<<(N + 7) / 8, 256, 0, stream>>>(gbuf, rowp, colx, dinv, bl + (size_t)j * OUT_F, mask, y, xl_out, N);
        xl_cur = xl_out;
    }

    fuse_k<<<(N + 7) / 8, 256, 0, stream>>>(hbuf, xl_cur, dw, Wf, bf, out, N);
}